// Round 5
// baseline (364.642 us; speedup 1.0000x reference)
//
#include <hip/hip_runtime.h>

// Fused Conv1d with mean + threshold channels.
// x: [64, 1, 100000] f32 ; W: [62, 1, 19] f32 ; b: [62] f32
// out: [64, 64, 20000] f32  (ch0 = windowed mean, ch1 = threshold, ch2..63 = conv)
//
// Structure: 4 consecutive positions/thread, window in registers,
// float4 stores, weights via wave-uniform global reads (s_load path, no LDS).

#define BATCH   64
#define LIN     100000
#define LOUT    20000
#define KSZ     19
#define STRIDE_ 5
#define PAD_    9
#define CSTD    62
#define UPPER_  2.99f
#define LOWER_  (-2.99f)

#define TPB         256
#define PPT         4                        // consecutive positions per thread
#define POS_PER_BLK (TPB * PPT)              // 1024
#define BPR         ((LOUT + POS_PER_BLK - 1) / POS_PER_BLK)   // 20
#define TILE_IN     ((POS_PER_BLK - 1) * STRIDE_ + KSZ)        // 5134
#define TILE_SZ     5136                     // padded to float4 multiple

__global__ __launch_bounds__(TPB)
void conv1d_mean_thr_kernel(const float* __restrict__ x,
                            const float* __restrict__ W,
                            const float* __restrict__ bias,
                            float* __restrict__ out)
{
    __shared__ float tile[TILE_SZ];

    const int tid   = threadIdx.x;
    const int blk   = blockIdx.x;
    const int batch = blk / BPR;
    const int pblk  = blk - batch * BPR;
    const int p0    = pblk * POS_PER_BLK;
    const long tstart = (long)p0 * STRIDE_ - PAD_;

    // ---- stage input tile (zero-fill outside [0, LIN)) ----
    const float* xrow = x + (size_t)batch * LIN;
    for (int i = tid; i < TILE_SZ; i += TPB) {
        long g = tstart + i;
        tile[i] = (g >= 0 && g < LIN) ? xrow[g] : 0.0f;
    }
    __syncthreads();

    // ---- per-thread window: 9 x float4 LDS reads -> 36 floats in registers ----
    // lane t reads granules 5t..5t+8 : (5t+k)%8 covers all 8 bank-groups -> conflict-free
    float xw[36];
    {
        const float4* t4 = reinterpret_cast<const float4*>(tile);
#pragma unroll
        for (int k = 0; k < 9; ++k) {
            float4 v = t4[tid * 5 + k];
            xw[4 * k + 0] = v.x;
            xw[4 * k + 1] = v.y;
            xw[4 * k + 2] = v.z;
            xw[4 * k + 3] = v.w;
        }
    }

    const int pos0   = p0 + tid * PPT;              // first of 4 consecutive positions
    const bool valid = (pos0 + PPT - 1) < LOUT;     // LOUT%4==0 -> all-or-nothing
    float* outp = out + (size_t)batch * 64 * LOUT + pos0;

    // ---- channel 0 (mean) + channel 1 (threshold) ----
    {
        float mean[PPT], thr[PPT];
        const float inv_k = 1.0f / (float)KSZ;
#pragma unroll
        for (int j = 0; j < PPT; ++j) {
            float s = 0.f, mx = -INFINITY, mn = INFINITY;
#pragma unroll
            for (int k = 0; k < KSZ; ++k) {
                float v = xw[5 * j + k];
                s += v; mx = fmaxf(mx, v); mn = fminf(mn, v);
            }
            mean[j] = s * inv_k;
            thr[j]  = (mx > UPPER_) ? 1.0f : ((mn < LOWER_) ? -1.0f : 0.0f);
        }
        if (valid) {
            *reinterpret_cast<float4*>(outp) =
                make_float4(mean[0], mean[1], mean[2], mean[3]);
            *reinterpret_cast<float4*>(outp + LOUT) =
                make_float4(thr[0], thr[1], thr[2], thr[3]);
        }
    }

    // ---- channels 2..63: standard conv, weights via uniform (scalar) loads ----
    for (int c = 0; c < CSTD; ++c) {
        float w[KSZ];
#pragma unroll
        for (int k = 0; k < KSZ; ++k) w[k] = W[c * KSZ + k];   // uniform -> s_load
        const float bv = bias[c];

        float acc[PPT];
#pragma unroll
        for (int j = 0; j < PPT; ++j) {
            float a = 0.f;
#pragma unroll
            for (int k = 0; k < KSZ; ++k)
                a = fmaf(xw[5 * j + k], w[k], a);
            acc[j] = a + bv;
        }
        if (valid) {
            *reinterpret_cast<float4*>(outp + (size_t)(c + 2) * LOUT) =
                make_float4(acc[0], acc[1], acc[2], acc[3]);
        }
    }
}

extern "C" void kernel_launch(void* const* d_in, const int* in_sizes, int n_in,
                              void* d_out, int out_size, void* d_ws, size_t ws_size,
                              hipStream_t stream)
{
    const float* x    = (const float*)d_in[0];
    const float* W    = (const float*)d_in[1];
    const float* bias = (const float*)d_in[2];
    float* out        = (float*)d_out;

    dim3 grid(BATCH * BPR);
    dim3 block(TPB);
    conv1d_mean_thr_kernel<<<grid, block, 0, stream>>>(x, W, bias, out);
}